// Round 4
// baseline (128.765 us; speedup 1.0000x reference)
//
#include <hip/hip_runtime.h>
#include <math.h>

// Problem constants (fixed by setup_inputs): B=8, C=4, H=W=64, K=8192
#define N_POINTS 32768   // B*H*W
#define KCODES   8192
#define HW       4096
#define CHW      16384

#define NSEG    64                 // code segments (grid.y)
#define SEGLEN  (KCODES / NSEG)    // 128 codes per segment
#define PPT     4                  // points per thread
#define BLOCK   512
#define PTILE   (BLOCK * PPT)      // 2048 points per block
#define GRIDX   (N_POINTS / PTILE) // 16

// ws layout: packed u64[32768] @ 0  ((sortable(best_d2)<<32)|best_k)
#define WS_PACKED 0

typedef float f2 __attribute__((ext_vector_type(2)));
typedef float f4 __attribute__((ext_vector_type(4)));

// Packed fp32: 2 IEEE-RN fp32 ops per issue slot; bitwise == scalar per half.
// (R3 verified absmax=0.0 with this exact formulation.)
static __device__ __forceinline__ f2 pk_mul(f2 a, f2 b) {
  f2 d;
  asm("v_pk_mul_f32 %0, %1, %2" : "=v"(d) : "v"(a), "v"(b));
  return d;
}
static __device__ __forceinline__ f2 pk_add(f2 a, f2 b) {
  f2 d;
  asm("v_pk_add_f32 %0, %1, %2" : "=v"(d) : "v"(a), "v"(b));
  return d;
}

// Bit-exact conv z = W x + b, numpy sequential c-order, no FMA contraction.
__device__ __forceinline__ void compute_z(
    const float* __restrict__ ze, const float* __restrict__ w,
    const float* __restrict__ bias, int n, float zo[4], float& zz) {
  int b = n >> 12, hw = n & 4095;
  const float* p = ze + b * CHW + hw;
  float x0 = p[0], x1 = p[HW], x2 = p[2 * HW], x3 = p[3 * HW];
#pragma unroll
  for (int o = 0; o < 4; ++o) {
    float acc = __fmul_rn(x0, w[o * 4 + 0]);
    acc = __fadd_rn(acc, __fmul_rn(x1, w[o * 4 + 1]));
    acc = __fadd_rn(acc, __fmul_rn(x2, w[o * 4 + 2]));
    acc = __fadd_rn(acc, __fmul_rn(x3, w[o * 4 + 3]));
    zo[o] = __fadd_rn(acc, bias[o]);
  }
  float s = __fmul_rn(zo[0], zo[0]);
  s = __fadd_rn(s, __fmul_rn(zo[1], zo[1]));
  s = __fadd_rn(s, __fmul_rn(zo[2], zo[2]));
  s = __fadd_rn(s, __fmul_rn(zo[3], zo[3]));
  zz = s;
}

// ---------------- Kernel S: segmented scan, pk-fp32 + atomicMin ------------
// R0 structure (PPT-amortized LDS broadcast + cross-block u64 atomicMin) with
// R3 arithmetic (v_pk halves the dot/bias chain). Cost model (per CU):
// VALU 0.117 instr/pair -> 61k cyc (25.6us); DS 5 b128/1024 pairs x ~10cyc
// -> 51k cyc (21us, hidden under VALU). R3's failure mode (DS-bound at
// PPT=2: 102k cyc DS) is avoided by PPT=4; PPT=8 rejected: duplicated-f2
// z-state would push VGPR past the 128 occupancy cliff.
// Rounding chain (bitwise == ref, R3-verified):
//   m_i = -2*c_i (exact);  dn = fl-chain(z0m0+z1m1+z2m2+z3m3) = -fl(2*dot)
//   s = (zz + dn) + cn  ==  (|z|^2 - 2*dot) + |c|^2 left-to-right
__global__ __launch_bounds__(512, 4) void vq_scan(
    const float* __restrict__ ze, const float* __restrict__ w,
    const float* __restrict__ bias, const float* __restrict__ cb,
    unsigned long long* __restrict__ packed) {
  __shared__ float sm[5][SEGLEN] __attribute__((aligned(16)));
  int tid = threadIdx.x;
  int k0 = blockIdx.y * SEGLEN;

  // stage segment: threads 0..127 transform one code each (-2c SoA + |c|^2)
  if (tid < SEGLEN) {
    f4 c = ((const f4*)cb)[k0 + tid];
    sm[0][tid] = __fmul_rn(-2.f, c.x);
    sm[1][tid] = __fmul_rn(-2.f, c.y);
    sm[2][tid] = __fmul_rn(-2.f, c.z);
    sm[3][tid] = __fmul_rn(-2.f, c.w);
    float cn = __fmul_rn(c.x, c.x);
    cn = __fadd_rn(cn, __fmul_rn(c.y, c.y));
    cn = __fadd_rn(cn, __fmul_rn(c.z, c.z));
    cn = __fadd_rn(cn, __fmul_rn(c.w, c.w));
    sm[4][tid] = cn;
  }

  // conv for this thread's 4 points while staging lands (coalesced: n0+512p)
  int n0 = blockIdx.x * PTILE + tid;
  f2 zd[PPT][4], zzd[PPT];
  float best[PPT];
  int bidx[PPT];
#pragma unroll
  for (int p = 0; p < PPT; ++p) {
    float z[4], zz;
    compute_z(ze, w, bias, n0 + BLOCK * p, z, zz);
#pragma unroll
    for (int c = 0; c < 4; ++c) zd[p][c] = (f2){z[c], z[c]};
    zzd[p] = (f2){zz, zz};
    best[p] = INFINITY;
    bidx[p] = 0;
  }
  __syncthreads();

#pragma unroll 2
  for (int j = 0; j < SEGLEN; j += 4) {
    f4 q0 = *(const f4*)&sm[0][j];   // -2c0 for codes j..j+3 (broadcast)
    f4 q1 = *(const f4*)&sm[1][j];
    f4 q2 = *(const f4*)&sm[2][j];
    f4 q3 = *(const f4*)&sm[3][j];
    f4 qn = *(const f4*)&sm[4][j];   // |c|^2
#pragma unroll
    for (int p = 0; p < PPT; ++p) {
      f2 dA = pk_mul(zd[p][0], q0.xy);
      dA = pk_add(dA, pk_mul(zd[p][1], q1.xy));
      dA = pk_add(dA, pk_mul(zd[p][2], q2.xy));
      dA = pk_add(dA, pk_mul(zd[p][3], q3.xy));
      f2 sA = pk_add(pk_add(zzd[p], dA), qn.xy);
      f2 dB = pk_mul(zd[p][0], q0.zw);
      dB = pk_add(dB, pk_mul(zd[p][1], q1.zw));
      dB = pk_add(dB, pk_mul(zd[p][2], q2.zw));
      dB = pk_add(dB, pk_mul(zd[p][3], q3.zw));
      f2 sB = pk_add(pk_add(zzd[p], dB), qn.zw);
      // ascending k, strict < : first-min (segment-local index, 0..127)
      if (sA.x < best[p]) { best[p] = sA.x; bidx[p] = j + 0; }
      if (sA.y < best[p]) { best[p] = sA.y; bidx[p] = j + 1; }
      if (sB.x < best[p]) { best[p] = sB.x; bidx[p] = j + 2; }
      if (sB.y < best[p]) { best[p] = sB.y; bidx[p] = j + 3; }
    }
  }

#pragma unroll
  for (int p = 0; p < PPT; ++p) {
    // pack (sortable float, global k): u64 min == (min d2, then min k)
    unsigned int u = __float_as_uint(best[p]);
    unsigned int so = (u & 0x80000000u) ? ~u : (u | 0x80000000u);
    unsigned long long key =
        ((unsigned long long)so << 32) | (unsigned int)(k0 + bidx[p]);
    atomicMin(&packed[n0 + BLOCK * p], key);
  }
}

// ---------------- Kernel F: decode, gather, latent write, loss -------------
// Unchanged from the 115.8us baseline (bit-exact, absmax=0 proven).
__global__ __launch_bounds__(256) void vq_finish(
    const float* __restrict__ ze, const float* __restrict__ w,
    const float* __restrict__ bias, const float* __restrict__ cb,
    const unsigned long long* __restrict__ packed, float* __restrict__ out) {
  int n = blockIdx.x * 256 + threadIdx.x;
  int bidx = (unsigned int)(packed[n] & 0xFFFFFFFFull);
  float4 c = ((const float4*)cb)[bidx];     // bit-exact gather (16B aligned)
  int b = n >> 12, hw = n & 4095;
  float* o = out + b * CHW + hw;
  o[0] = c.x; o[HW] = c.y; o[2 * HW] = c.z; o[3 * HW] = c.w;
  float z[4], zz;
  compute_z(ze, w, bias, n, z, zz);
  float d0 = c.x - z[0], d1 = c.y - z[1], d2 = c.z - z[2], d3 = c.w - z[3];
  float e = d0 * d0 + d1 * d1 + d2 * d2 + d3 * d3;
#pragma unroll
  for (int off = 32; off > 0; off >>= 1) e += __shfl_down(e, off, 64);
  __shared__ float sred[4];
  if ((threadIdx.x & 63) == 0) sred[threadIdx.x >> 6] = e;
  __syncthreads();
  if (threadIdx.x == 0) {
    float t = (sred[0] + sred[1]) + (sred[2] + sred[3]);
    // q_loss = (1 + BETA) * mean over 131072 elements
    atomicAdd(out + (N_POINTS * 4), t * (1.25f / 131072.f));
  }
}

extern "C" void kernel_launch(void* const* d_in, const int* in_sizes, int n_in,
                              void* d_out, int out_size, void* d_ws, size_t ws_size,
                              hipStream_t stream) {
  const float* ze   = (const float*)d_in[0];  // z_e_in [8,4,64,64]
  const float* w    = (const float*)d_in[1];  // pq_w [4,4]
  const float* bias = (const float*)d_in[2];  // pq_b [4]
  const float* cb   = (const float*)d_in[3];  // codebook [8192,4]

  unsigned long long* packed =
      (unsigned long long*)((char*)d_ws + WS_PACKED);
  float* out = (float*)d_out;

  // poison packed (0xFF bytes == u64 all-ones == sortable max) + zero loss
  hipMemsetAsync(packed, 0xFF, N_POINTS * sizeof(unsigned long long), stream);
  hipMemsetAsync((char*)d_out + (size_t)N_POINTS * 4 * sizeof(float), 0,
                 sizeof(float), stream);
  vq_scan<<<dim3(GRIDX, NSEG), BLOCK, 0, stream>>>(ze, w, bias, cb, packed);
  vq_finish<<<128, 256, 0, stream>>>(ze, w, bias, cb, packed, out);
}